// Round 1
// 786.997 us; speedup vs baseline: 1.0102x; 1.0102x over previous
//
#include <hip/hip_runtime.h>
#include <hip/hip_fp16.h>

// MoE gate: logits = x @ W^T (M=32768, N=64, K=4096 fp32), softmax over 64,
// top-8 (vals fp32, idx as float). Split-f16 MFMA GEMM:
//   x = xh + xl, 64*W = wh + wl  (f16 each); logit = (xh*wh + xl*wh + xh*wl)/64
// Logit noise vs fp32 ref ~2e-6. Near-tie ranks in the top-9 (rel gap < 5e-5)
// are flagged and re-resolved exactly in fp64 by a second tiny kernel.
//
// V2 structure (this round):
//  * W is split ONCE per launch by moe_pack_w into workspace, stored in MFMA
//    B-fragment blob order; the gate pulls it with global_load_lds into a
//    double-buffered LDS pair (no W split VALU / no W VGPRs in the hot loop).
//  * x is loaded DIRECTLY per-fragment into registers (A-frag layout
//    row=l&15, k=(l>>4)*8+j is two float4 per lane from row-major x) and
//    split in-register: no x LDS, no ds_writes, no x barrier.
//  * ONE barrier per chunk; all prefetch (W-DMA + x regs for kc+1) is issued
//    at the top of the MFMA phase so the vmcnt drain at the barrier lands
//    after ~600 cycles of MFMA instead of before it.
// Numerics are bit-identical to the previous (verified) version: same split
// math, same MFMA accumulation order, same W*64 scaling.

typedef _Float16 half8 __attribute__((ext_vector_type(8)));
typedef float floatx4 __attribute__((ext_vector_type(4)));

constexpr int D = 4096;      // d_hidden
constexpr int NE = 64;       // experts
constexpr int MBLK = 64;     // tokens per block
constexpr int BK = 64;       // k per chunk
constexpr int KCHUNKS = D / BK;

// Workspace layout: [0,16) flag counter | [16, 16+4*cap) flag list (cap<=32768,
// ends < 131 KB) | [256 KB, 256K+512K) Wh blobs | [+512K, +1M) Wl blobs.
// Harness workspace is ~2 GiB (poison fills show 2.147 GB writes) — plenty.
constexpr size_t WPACK_OFF  = 1u << 18;        // 256 KB
constexpr size_t WPACK_HALF = (size_t)KCHUNKS * NE * BK;  // halfs per operand

__device__ __forceinline__ void split8s(float4 p, float4 q, float sc, half8& h, half8& l) {
    float f[8] = {p.x, p.y, p.z, p.w, q.x, q.y, q.z, q.w};
#pragma unroll
    for (int i = 0; i < 8; ++i) {
        float v = f[i] * sc;
        _Float16 hi = (_Float16)v;
        h[i] = hi;
        l[i] = (_Float16)(v - (float)hi);
    }
}

// 16-byte async global->LDS copy (wave-uniform LDS base + lane*16 dest).
__device__ __forceinline__ void async16(const _Float16* g, _Float16* lds) {
    __builtin_amdgcn_global_load_lds(
        (__attribute__((address_space(1))) uint32_t*)g,
        (__attribute__((address_space(3))) uint32_t*)lds, 16, 0, 0);
}

// Split W into f16 hi/lo blobs, in the exact MFMA B-fragment blob order the
// gate kernel reads: slot (e,k8) -> (((e>>4)*2+(k8>>2))*64 + (k8&3)*16 + (e&15))*8.
__global__ __launch_bounds__(256) void moe_pack_w(
    const float* __restrict__ wg, _Float16* __restrict__ whp, _Float16* __restrict__ wlp)
{
    const int kc = (int)blockIdx.x;
    const int tid = (int)threadIdx.x;
#pragma unroll
    for (int r = 0; r < 2; ++r) {
        const int s = tid + r * 256;           // 512 slots per chunk
        const int e = s >> 3, k8 = s & 7;
        const float* src = wg + (size_t)e * D + kc * BK + k8 * 8;
        float4 a = *(const float4*)src;
        float4 b = *(const float4*)(src + 4);
        half8 h, l;
        split8s(a, b, 64.0f, h, l);            // scale W by 64: wl stays normal-range f16
        const int off = (((e >> 4) * 2 + (k8 >> 2)) * 64 + (k8 & 3) * 16 + (e & 15)) * 8;
        *(half8*)(whp + (size_t)kc * 4096 + off) = h;
        *(half8*)(wlp + (size_t)kc * 4096 + off) = l;
    }
}

__global__ __launch_bounds__(256, 2) void moe_gate_kernel(
    const float* __restrict__ x,
    const _Float16* __restrict__ whp, const _Float16* __restrict__ wlp,
    float* __restrict__ out_vals, float* __restrict__ out_idx,
    int* __restrict__ flag_ws, int cap)
{
    __shared__ alignas(16) _Float16 WhB[2 * NE * BK];   // 16 KB (double buffer)
    __shared__ alignas(16) _Float16 WlB[2 * NE * BK];   // 16 KB

    const int tid  = (int)threadIdx.x;
    const int lane = tid & 63;
    const int wv   = tid >> 6;             // wave id == M-tile id
    const int tb   = (int)blockIdx.x * MBLK;

    // Direct A-fragment pointers: row = tb + wv*16 + (lane&15), base col (lane>>4)*8.
    // Per chunk kc, ks: float4 at +kc*64 + ks*32 (+4). Each x element is loaded
    // by exactly one lane (fragments partition the 64x64 tile).
    const float* xp = x + (size_t)(tb + wv * 16 + (lane & 15)) * D + (lane >> 4) * 8;

    // W DMA addressing: chunk blob is 4096 halfs; wave wv copies 2x1KB rounds.
    const int wgo = wv * 1024 + lane * 8;  // per-lane global offset (halfs)
    const int wlo = wv * 1024;             // wave-uniform LDS offset (halfs)

    floatx4 acc[4] = {{0,0,0,0},{0,0,0,0},{0,0,0,0},{0,0,0,0}};

    // Prologue: W chunk 0 -> buf 0; x chunk 0 -> regs A.
    async16(whp + wgo,       WhB + wlo);
    async16(whp + wgo + 512, WhB + wlo + 512);
    async16(wlp + wgo,       WlB + wlo);
    async16(wlp + wgo + 512, WlB + wlo + 512);
    float4 A0 = *(const float4*)(xp);
    float4 A1 = *(const float4*)(xp + 4);
    float4 A2 = *(const float4*)(xp + 32);
    float4 A3 = *(const float4*)(xp + 36);
    float4 B0, B1, B2, B3;
    asm volatile("s_waitcnt vmcnt(0)" ::: "memory");
    __syncthreads();

    auto body = [&](int kc, float4& C0, float4& C1, float4& C2, float4& C3,
                    float4& N0, float4& N1, float4& N2, float4& N3) {
        // --- prefetch kc+1 (issued at top of MFMA phase; drains at the barrier
        //     below, i.e. after the compute, not before it) ---
        if (kc + 1 < KCHUNKS) {
            const int nb = (kc + 1) & 1;     // safe: buf nb last read in chunk kc-1,
                                             // all waves passed the kc-1 barrier
            const _Float16* gh = whp + (size_t)(kc + 1) * 4096 + wgo;
            const _Float16* gl = wlp + (size_t)(kc + 1) * 4096 + wgo;
            async16(gh,       WhB + nb * 4096 + wlo);
            async16(gh + 512, WhB + nb * 4096 + wlo + 512);
            async16(gl,       WlB + nb * 4096 + wlo);
            async16(gl + 512, WlB + nb * 4096 + wlo + 512);
            const float* xn = xp + (kc + 1) * 64;
            N0 = *(const float4*)(xn);
            N1 = *(const float4*)(xn + 4);
            N2 = *(const float4*)(xn + 32);
            N3 = *(const float4*)(xn + 36);
        }
        // --- split current x fragments in-register (16 elems/thread) ---
        half8 ah0, al0, ah1, al1;
        split8s(C0, C1, 1.0f, ah0, al0);     // ks = 0
        split8s(C2, C3, 1.0f, ah1, al1);     // ks = 1
        // --- MFMA phase: B frags from LDS (lane*16B contiguous, conflict-free) ---
        const _Float16* wh = WhB + (kc & 1) * 4096;
        const _Float16* wl = WlB + (kc & 1) * 4096;
#pragma unroll
        for (int nt = 0; nt < 4; ++nt) {
            const half8 bh = *(const half8*)(wh + ((nt * 2 + 0) * 64 + lane) * 8);
            const half8 bl = *(const half8*)(wl + ((nt * 2 + 0) * 64 + lane) * 8);
            acc[nt] = __builtin_amdgcn_mfma_f32_16x16x32_f16(ah0, bh, acc[nt], 0, 0, 0);
            acc[nt] = __builtin_amdgcn_mfma_f32_16x16x32_f16(al0, bh, acc[nt], 0, 0, 0);
            acc[nt] = __builtin_amdgcn_mfma_f32_16x16x32_f16(ah0, bl, acc[nt], 0, 0, 0);
        }
#pragma unroll
        for (int nt = 0; nt < 4; ++nt) {
            const half8 bh = *(const half8*)(wh + ((nt * 2 + 1) * 64 + lane) * 8);
            const half8 bl = *(const half8*)(wl + ((nt * 2 + 1) * 64 + lane) * 8);
            acc[nt] = __builtin_amdgcn_mfma_f32_16x16x32_f16(ah1, bh, acc[nt], 0, 0, 0);
            acc[nt] = __builtin_amdgcn_mfma_f32_16x16x32_f16(al1, bh, acc[nt], 0, 0, 0);
            acc[nt] = __builtin_amdgcn_mfma_f32_16x16x32_f16(ah1, bl, acc[nt], 0, 0, 0);
        }
        // --- single barrier per chunk: drains DMA + x loads for kc+1 ---
        asm volatile("s_waitcnt vmcnt(0)" ::: "memory");
        __syncthreads();
    };

    for (int kc = 0; kc < KCHUNKS; kc += 2) {
        body(kc,     A0, A1, A2, A3, B0, B1, B2, B3);
        body(kc + 1, B0, B1, B2, B3, A0, A1, A2, A3);
    }

    // Epilogue: lane holds experts {nt*16 + (lane&15)} for tokens
    // tb + wv*16 + (lane>>4)*4 + r. Softmax + top-9 via 16-lane xor-shuffles;
    // adjacent near-ties (rel gap < 5e-5) flag the token for fp64 refinement.
    const int g = lane >> 4, c = lane & 15;
    const float inv64 = 0.015625f;           // undo W*64 scale (exact pow2)
#pragma unroll
    for (int r = 0; r < 4; ++r) {
        float s[4];
#pragma unroll
        for (int nt = 0; nt < 4; ++nt) s[nt] = acc[nt][r] * inv64;
        float m = fmaxf(fmaxf(s[0], s[1]), fmaxf(s[2], s[3]));
#pragma unroll
        for (int off = 1; off < 16; off <<= 1) m = fmaxf(m, __shfl_xor(m, off));
        float p[4]; float t = 0.0f;
#pragma unroll
        for (int nt = 0; nt < 4; ++nt) { p[nt] = expf(s[nt] - m); t += p[nt]; }
#pragma unroll
        for (int off = 1; off < 16; off <<= 1) t += __shfl_xor(t, off);
        const float inv = 1.0f / t;
#pragma unroll
        for (int nt = 0; nt < 4; ++nt) p[nt] *= inv;

        const int tok = tb + wv * 16 + g * 4 + r;
        float prev = 0.0f;
        bool flagged = false;
#pragma unroll
        for (int i = 0; i < 9; ++i) {
            float bv = p[0]; int bn = 0;
            if (p[1] > bv) { bv = p[1]; bn = 1; }   // strict > : ties -> lower expert
            if (p[2] > bv) { bv = p[2]; bn = 2; }
            if (p[3] > bv) { bv = p[3]; bn = 3; }
            int be = bn * 16 + c;
#pragma unroll
            for (int off = 1; off < 16; off <<= 1) {
                float ov = __shfl_xor(bv, off);
                int   oe = __shfl_xor(be, off);
                if (ov > bv || (ov == bv && oe < be)) { bv = ov; be = oe; }
            }
            if (i > 0 && (prev - bv) < prev * 5e-5f) flagged = true;
            prev = bv;
            if (i < 8 && c == i) {
                out_vals[(size_t)tok * 8 + i] = bv;
                out_idx [(size_t)tok * 8 + i] = (float)be;
            }
            if (c == (be & 15)) p[be >> 4] = -1.0f; // remove winner (scores >= 0)
        }
        if (flagged && c == 0 && cap > 0) {
            int pos = atomicAdd(flag_ws, 1);
            if (pos < cap) flag_ws[4 + pos] = tok;
        }
    }
}

// fp64 exact re-resolution for flagged tokens (near-tied top-9 ranks).
// 256 thr = 64 experts x 4 k-chunks; fp64 dot, LDS reduce, wave-0 fp64
// softmax + top-8 (lower-index tie-break, matches lax.top_k / np).
__global__ __launch_bounds__(256) void moe_refine_kernel(
    const float* __restrict__ x, const float* __restrict__ wg,
    float* __restrict__ out_vals, float* __restrict__ out_idx,
    const int* __restrict__ flag_ws, int cap)
{
    const int count = min(flag_ws[0], cap);
    const int* list = flag_ws + 4;
    __shared__ double part[256];
    for (int it = (int)blockIdx.x; it < count; it += (int)gridDim.x) {
        const int tok = list[it];
        const int e = (int)threadIdx.x & 63, ch = (int)threadIdx.x >> 6;
        const float4* xr = (const float4*)(x + (size_t)tok * D + ch * 1024);
        const float4* wr = (const float4*)(wg + (size_t)e * D + ch * 1024);
        double s0 = 0, s1 = 0, s2 = 0, s3 = 0;
#pragma unroll 4
        for (int k = 0; k < 256; ++k) {
            float4 a = xr[k], b = wr[k];
            s0 += (double)a.x * (double)b.x; s1 += (double)a.y * (double)b.y;
            s2 += (double)a.z * (double)b.z; s3 += (double)a.w * (double)b.w;
        }
        part[threadIdx.x] = (s0 + s1) + (s2 + s3);
        __syncthreads();
        if (threadIdx.x < 64) {
            double l = part[e] + part[e + 64] + part[e + 128] + part[e + 192];
            double m = l;
#pragma unroll
            for (int off = 1; off < 64; off <<= 1) m = fmax(m, __shfl_xor(m, off));
            double p = exp(l - m), Z = p;
#pragma unroll
            for (int off = 1; off < 64; off <<= 1) Z += __shfl_xor(Z, off);
            double key = l;
            for (int i = 0; i < 8; ++i) {
                double bk = key; int bi = e; double bp = p;
#pragma unroll
                for (int off = 1; off < 64; off <<= 1) {
                    double ok = __shfl_xor(bk, off);
                    int    oi = __shfl_xor(bi, off);
                    double op = __shfl_xor(bp, off);
                    if (ok > bk || (ok == bk && oi < bi)) { bk = ok; bi = oi; bp = op; }
                }
                if (e == i) {
                    out_vals[(size_t)tok * 8 + i] = (float)(bp / Z);
                    out_idx [(size_t)tok * 8 + i] = (float)bi;
                }
                if (e == bi) key = -1.0e300;
            }
        }
        __syncthreads();
    }
}

extern "C" void kernel_launch(void* const* d_in, const int* in_sizes, int n_in,
                              void* d_out, int out_size, void* d_ws, size_t ws_size,
                              hipStream_t stream) {
    const float* x  = (const float*)d_in[0];
    const float* wg = (const float*)d_in[1];
    const int n_tokens = in_sizes[0] / D;           // 32768
    float* out_vals = (float*)d_out;
    float* out_idx  = out_vals + (size_t)n_tokens * 8;
    _Float16* whp = (_Float16*)((char*)d_ws + WPACK_OFF);
    _Float16* wlp = whp + WPACK_HALF;
    int cap = 0;
    if (ws_size > 32) {
        size_t c = (ws_size - 32) / sizeof(int);
        cap = (int)(c > 32768 ? 32768 : c);
    }
    hipMemsetAsync(d_ws, 0, 16, stream);            // zero flag counter (ws re-poisoned 0xAA)
    hipLaunchKernelGGL(moe_pack_w, dim3(KCHUNKS), dim3(256), 0, stream, wg, whp, wlp);
    const int grid = n_tokens / MBLK;               // 512 blocks
    hipLaunchKernelGGL(moe_gate_kernel, dim3(grid), dim3(256), 0, stream,
                       x, whp, wlp, out_vals, out_idx, (int*)d_ws, cap);
    hipLaunchKernelGGL(moe_refine_kernel, dim3(256), dim3(256), 0, stream,
                       x, wg, out_vals, out_idx, (const int*)d_ws, cap);
}